// Round 4
// baseline (264.542 us; speedup 1.0000x reference)
//
#include <hip/hip_runtime.h>

// Problem constants (from reference)
#define ZD_ 64
#define PD_ 16
#define DH_ 128

// ---------------------------------------------------------------------------
// K0: hid[64][128] = relu([z_all | pde] @ W1^T + b1)
// ---------------------------------------------------------------------------
__global__ void hid_kernel(const float* __restrict__ z_all,
                           const float* __restrict__ W1,
                           const float* __restrict__ b1,
                           const float* __restrict__ pde,
                           float* __restrict__ hid) {
    int gid = blockIdx.x * 256 + threadIdx.x;   // 8192 outputs
    int r = gid >> 7;                            // z row (0..63)
    int d = gid & 127;                           // hidden unit
    const float* w = W1 + d * (ZD_ + PD_);
    const float* z = z_all + r * ZD_;
    float acc = b1[d];
    #pragma unroll 8
    for (int c = 0; c < ZD_; ++c) acc += z[c] * w[c];
    #pragma unroll
    for (int c = 0; c < PD_; ++c) acc += pde[c] * w[ZD_ + c];
    hid[gid] = fmaxf(acc, 0.0f);
}

// ---------------------------------------------------------------------------
// K1 (fused): exe GEMM + outer product, W2 read in NATIVE layout (no
// transpose pass, no exe intermediate).
//   exe[o][i][kk] = hid[hk] . W2[n] + b2[n],  n = ob*576 + ib*9 + kk
//   out[o][i][k][l] = exe[o][i][k] * unet[o][i][l]
//   o = h*64+ob ; i = kb*64+ib ; hk = h*8+kb
// Thread = one (o,i) pair: 9 dot-products of length 128 over its 9
// contiguous W2 rows (float4 loads along k). hid row is wave-uniform
// (kb = i>>6 constant per 64-lane wave) -> broadcast loads into 16 float4
// regs per 64-wide k-half. The 81 outputs go through LDS (lane stride 81,
// 81 mod 32 = 17 coprime -> conflict-free) and stream out as coalesced
// float4: block's out region = 128*81 = 10368 contiguous floats.
// Grid: 512 o x 4 i-halves = 2048 blocks x 128 threads.
// ---------------------------------------------------------------------------
__global__ __launch_bounds__(128) void fused_kernel(
        const float* __restrict__ hid,
        const float* __restrict__ W2,
        const float* __restrict__ b2,
        const float* __restrict__ unet,
        float* __restrict__ out) {
    __shared__ __align__(16) float s_out[128 * 81];   // 41472 B
    int b   = blockIdx.x;
    int o   = b >> 2;
    int i0  = (b & 3) * 128;
    int tid = threadIdx.x;
    int i   = i0 + tid;
    int h   = o >> 6, ob = o & 63;
    int kb  = i >> 6, ib = i & 63;
    int n0  = ob * 576 + ib * 9;
    const float* hrow = hid + (size_t)(h * 8 + kb) * DH_;   // wave-uniform

    float acc[9];
    #pragma unroll
    for (int r = 0; r < 9; ++r) acc[r] = b2[n0 + r];

    #pragma unroll
    for (int kh = 0; kh < 2; ++kh) {                 // k in two 64-wide halves
        float4 hreg[16];
        #pragma unroll
        for (int q = 0; q < 16; ++q)
            hreg[q] = *reinterpret_cast<const float4*>(hrow + kh * 64 + q * 4);
        #pragma unroll 3
        for (int r = 0; r < 9; ++r) {
            const float* wr = W2 + (size_t)(n0 + r) * DH_ + kh * 64;
            float a = acc[r];
            #pragma unroll
            for (int q = 0; q < 16; ++q) {
                float4 w = *reinterpret_cast<const float4*>(wr + q * 4);
                a += hreg[q].x * w.x + hreg[q].y * w.y
                   + hreg[q].z * w.z + hreg[q].w * w.w;
            }
            acc[r] = a;
        }
    }

    const float* up = unet + (size_t)(o * 512 + i) * 9;
    float uv[9];
    #pragma unroll
    for (int l = 0; l < 9; ++l) uv[l] = up[l];

    float* so = s_out + tid * 81;
    #pragma unroll
    for (int r = 0; r < 9; ++r) {
        #pragma unroll
        for (int l = 0; l < 9; ++l) so[r * 9 + l] = acc[r] * uv[l];
    }
    __syncthreads();

    float4* o4 = reinterpret_cast<float4*>(out + (size_t)(o * 512 + i0) * 81);
    const float4* s4 = reinterpret_cast<const float4*>(s_out);
    for (int idx = tid; idx < 2592; idx += 128)      // 10368/4 coalesced stores
        o4[idx] = s4[idx];
}

// ---------------------------------------------------------------------------
extern "C" void kernel_launch(void* const* d_in, const int* in_sizes, int n_in,
                              void* d_out, int out_size, void* d_ws, size_t ws_size,
                              hipStream_t stream) {
    const float* z_all = (const float*)d_in[0];  // [64,64]
    const float* W1    = (const float*)d_in[1];  // [128,80]
    const float* b1    = (const float*)d_in[2];  // [128]
    const float* W2    = (const float*)d_in[3];  // [36864,128]
    const float* b2    = (const float*)d_in[4];  // [36864]
    const float* unet  = (const float*)d_in[5];  // [512,512,9]
    const float* pde   = (const float*)d_in[6];  // [16]
    float* out = (float*)d_out;                  // [512,512,9,9]

    float* hid = (float*)d_ws;                   // 8192 floats (fully rewritten each call)

    hid_kernel<<<32, 256, 0, stream>>>(z_all, W1, b1, pde, hid);
    fused_kernel<<<2048, 128, 0, stream>>>(hid, W2, b2, unet, out);
}

// Round 5
// 154.741 us; speedup vs baseline: 1.7096x; 1.7096x over previous
//
#include <hip/hip_runtime.h>

// Problem constants (from reference)
#define ZD_ 64
#define PD_ 16
#define DH_ 128
#define LDS_STRIDE 132     // 128 + 4 pad: keeps b128 16B-aligned (132*4 % 16 == 0)

// ---------------------------------------------------------------------------
// K0: hid[64][128] = relu([z_all | pde] @ W1^T + b1)
// ---------------------------------------------------------------------------
__global__ void hid_kernel(const float* __restrict__ z_all,
                           const float* __restrict__ W1,
                           const float* __restrict__ b1,
                           const float* __restrict__ pde,
                           float* __restrict__ hid) {
    int gid = blockIdx.x * 256 + threadIdx.x;   // 8192 outputs
    int r = gid >> 7;                            // z row (0..63)
    int d = gid & 127;                           // hidden unit
    const float* w = W1 + d * (ZD_ + PD_);
    const float* z = z_all + r * ZD_;
    float acc = b1[d];
    #pragma unroll 8
    for (int c = 0; c < ZD_; ++c) acc += z[c] * w[c];
    #pragma unroll
    for (int c = 0; c < PD_; ++c) acc += pde[c] * w[ZD_ + c];
    hid[gid] = fmaxf(acc, 0.0f);
}

// ---------------------------------------------------------------------------
// K1: exe GEMM, native-layout W2 via LDS staging (no transpose pass).
//   exe[o][i][kk] = hid[hk] . W2[n] + b2[n]
//   n = ob*576 + ib*9 + kk ; hk = h*8+kb ; o = h*64+ob ; i = kb*64+ib
// Block = 64 consecutive n (one contiguous 32KB W2 slab -> fully coalesced
// float4 loads; 64 | 576 so the block stays inside one ob). Wave w handles
// hk = w*16..w*16+15: hid rows are wave-uniform (readfirstlane) -> scalar
// s_load_dwordx4 broadcasts. Lane = one n; 16 accumulators; each LDS
// ds_read_b128 is reused 16x. Stores: lane-contiguous b32 per hk.
// Grid: 576 blocks x 256 threads. LDS 33.8KB -> 4 blocks/CU.
// ---------------------------------------------------------------------------
__global__ __launch_bounds__(256) void exe_kernel(
        const float* __restrict__ hid,
        const float* __restrict__ W2,
        const float* __restrict__ b2,
        float* __restrict__ exe) {
    __shared__ __align__(16) float s_tile[64 * LDS_STRIDE];
    int tid = threadIdx.x;
    int n0  = blockIdx.x * 64;

    // Stage W2[n0..n0+64) (8192 contiguous floats) into LDS, n-major.
    const float4* g4 = reinterpret_cast<const float4*>(W2 + (size_t)n0 * DH_);
    #pragma unroll
    for (int j = 0; j < 8; ++j) {
        int g  = j * 256 + tid;                 // 0..2047 float4s
        int nl = g >> 5;                        // row (0..63)
        int k0 = (g & 31) * 4;                  // k start
        *reinterpret_cast<float4*>(&s_tile[nl * LDS_STRIDE + k0]) = g4[g];
    }
    __syncthreads();

    int wave   = __builtin_amdgcn_readfirstlane(tid >> 6);
    int lane   = tid & 63;
    int hkbase = wave * 16;
    const float* hbase = hid + (size_t)hkbase * DH_;   // wave-uniform

    float bias = b2[n0 + lane];
    float acc[16];
    #pragma unroll
    for (int j = 0; j < 16; ++j) acc[j] = bias;

    const float* trow = s_tile + lane * LDS_STRIDE;
    #pragma unroll 4
    for (int c = 0; c < 32; ++c) {
        int k0 = c * 4;
        float4 v = *reinterpret_cast<const float4*>(trow + k0);   // ds_read_b128
        #pragma unroll
        for (int j = 0; j < 16; ++j) {
            float4 hv = *reinterpret_cast<const float4*>(hbase + j * DH_ + k0); // s_load
            acc[j] += hv.x * v.x + hv.y * v.y + hv.z * v.z + hv.w * v.w;
        }
    }

    int ob = n0 / 576;                           // block-uniform (64 | 576)
    int r  = n0 % 576 + lane;
    #pragma unroll
    for (int j = 0; j < 16; ++j) {
        int hk = hkbase + j;
        int h = hk >> 3, kb = hk & 7;
        exe[(size_t)(h * 64 + ob) * 4608 + kb * 576 + r] = acc[j];
    }
}

// ---------------------------------------------------------------------------
// K2: outer product with float4 stores (verified in R3).
//   out[o][i][k][l] = exe[o][i][k] * unet[o][i][l]
// Block = (o, c=kb): 576 exe + 576 unet floats in LDS; output region is
// 5184 contiguous floats = 1296 float4, fully-coalesced stores.
// ---------------------------------------------------------------------------
__global__ void outer_kernel(const float* __restrict__ exe,
                             const float* __restrict__ unet,
                             float* __restrict__ out) {
    __shared__ float s_e[576], s_u[576];
    int b = blockIdx.x;
    int o = b >> 3, c = b & 7;
    size_t base9 = (size_t)o * 4608 + (size_t)c * 576;
    const float4* e4 = reinterpret_cast<const float4*>(exe + base9);
    const float4* u4 = reinterpret_cast<const float4*>(unet + base9);
    int tid = threadIdx.x;
    if (tid < 144) {
        reinterpret_cast<float4*>(s_e)[tid] = e4[tid];
        reinterpret_cast<float4*>(s_u)[tid] = u4[tid];
    }
    __syncthreads();
    float4* o4 = reinterpret_cast<float4*>(out + (size_t)o * 41472 + (size_t)c * 5184);
    for (int idx = tid; idx < 1296; idx += 256) {
        int e0 = idx * 4;
        float4 v;
        float* vp = &v.x;
        #pragma unroll
        for (int j = 0; j < 4; ++j) {
            int e = e0 + j;
            int p = e / 81;
            int rem = e - p * 81;
            int k = rem / 9;
            int l = rem - k * 9;
            vp[j] = s_e[p * 9 + k] * s_u[p * 9 + l];
        }
        o4[idx] = v;
    }
}

// ---------------------------------------------------------------------------
extern "C" void kernel_launch(void* const* d_in, const int* in_sizes, int n_in,
                              void* d_out, int out_size, void* d_ws, size_t ws_size,
                              hipStream_t stream) {
    const float* z_all = (const float*)d_in[0];  // [64,64]
    const float* W1    = (const float*)d_in[1];  // [128,80]
    const float* b1    = (const float*)d_in[2];  // [128]
    const float* W2    = (const float*)d_in[3];  // [36864,128]
    const float* b2    = (const float*)d_in[4];  // [36864]
    const float* unet  = (const float*)d_in[5];  // [512,512,9]
    const float* pde   = (const float*)d_in[6];  // [16]
    float* out = (float*)d_out;                  // [512,512,9,9]

    float* ws  = (float*)d_ws;
    float* hid = ws;                             // 8192 floats
    float* exe = ws + 8192;                      // 512*512*9 = 2359296 floats

    hid_kernel<<<32, 256, 0, stream>>>(z_all, W1, b1, pde, hid);
    exe_kernel<<<576, 256, 0, stream>>>(hid, W2, b2, exe);
    outer_kernel<<<4096, 256, 0, stream>>>(exe, unet, out);
}